// Round 9
// baseline (239.202 us; speedup 1.0000x reference)
//
#include <hip/hip_runtime.h>

#define N_NODES 100000
#define D 128          // feature dim
#define K 16           // neighbors
#define CATK 256       // concat dim (2*D)
#define MB 32          // nodes per block (sage_mm)
#define PAD 8
#define LDSW (CATK + PAD)   // 264 bf16 elems -> 528 B row stride
#define ZW 132              // z-staging row stride in floats (528 B)
#define GW 32               // gather column-group width (32 cols = 32 B fp8)
#define NGRP 4              // 128/32 column groups

typedef __attribute__((ext_vector_type(8))) short bf16x8;
typedef __attribute__((ext_vector_type(4))) float f32x4;
typedef __attribute__((ext_vector_type(2))) float f32x2;

__device__ __forceinline__ unsigned short f2bf(float f) {
    union { float f; unsigned u; } v; v.f = f;
    unsigned u = v.u;
    return (unsigned short)((u + 0x7fffu + ((u >> 16) & 1u)) >> 16);  // RNE
}

// pack 4 floats -> 4 fp8 e4m3 bytes
__device__ __forceinline__ unsigned pk4(float a, float b, float c, float d) {
    int w = __builtin_amdgcn_cvt_pk_fp8_f32(a, b, 0, false);
    w = __builtin_amdgcn_cvt_pk_fp8_f32(c, d, w, true);
    return (unsigned)w;
}

// decode 4 fp8 bytes, accumulate into two packed f32x2 accumulators
__device__ __forceinline__ void dec4p(unsigned w, f32x2* a) {
    f32x2 lo = __builtin_amdgcn_cvt_pk_f32_fp8((int)w, false);
    f32x2 hi = __builtin_amdgcn_cvt_pk_f32_fp8((int)w, true);
    a[0] += lo;
    a[1] += hi;
}

// feats f32 -> fp8 table in COLUMN-BLOCKED layout f8c[grp][node][32B]
// (grp = col/32; 3.2 MB per group -> fits one XCD's 4 MB L2).
// Also Ws [2,256,128] f32 -> Wt [2,128,256] bf16 (transposed).
__global__ void cvt_all(const float* __restrict__ feats, const float* __restrict__ Ws,
                        unsigned char* __restrict__ f8c, unsigned short* __restrict__ Wt) {
    int tid = blockIdx.x * 256 + threadIdx.x;
    int i = tid * 16;
    if (i < N_NODES * D) {
        const float4* p = (const float4*)(feats + i);
        float4 v0 = p[0], v1 = p[1], v2 = p[2], v3 = p[3];
        uint4 o;
        o.x = pk4(v0.x, v0.y, v0.z, v0.w);
        o.y = pk4(v1.x, v1.y, v1.z, v1.w);
        o.z = pk4(v2.x, v2.y, v2.z, v2.w);
        o.w = pk4(v3.x, v3.y, v3.z, v3.w);
        int node = tid >> 3, sub = tid & 7;          // sub covers cols sub*16..+16
        *(uint4*)(f8c + ((size_t)(sub >> 1) * N_NODES + node) * GW + (sub & 1) * 16) = o;
    }
    if (tid < 2 * CATK * D) {
        int l = tid / (CATK * D);
        int r = tid % (CATK * D);
        int n = r / CATK, k = r % CATK;
        Wt[tid] = f2bf(Ws[l * CATK * D + k * D + n]);
    }
}

// Pure gather pass over the column-blocked table. One block = 128 nodes x one
// column group; grp = (blockIdx%8)>>1 pins each group to an XCD pair so the
// group's 3.2 MB region stays L2-resident (R8: split alone didn't pay; R0
// arithmetic says 12.8 MB table vs 4 MB L2/XCD was the gather-BW wall).
// Numerically identical to the fused path: f32 accumulate, *(1/16), f2bf.
__launch_bounds__(256, 4)
__global__ void gather_mean(const unsigned char* __restrict__ g8c,
                            const int* __restrict__ idx,
                            unsigned short* __restrict__ aggc) {
    const int t = threadIdx.x;
    const int wg = blockIdx.x;
    const int xcd = wg & 7;
    const int grp = xcd >> 1;                    // 0..3, fixed per XCD pair
    const int nodeblk = (wg >> 3) * 2 + (xcd & 1);  // 0..781
    const int m = t >> 1;                        // node within block (0..127)
    const int h = t & 1;                         // 16-B half of the 32-B slice
    const int node = nodeblk * 128 + m;
    if (node >= N_NODES) return;

    const int4* ip = (const int4*)(idx + (size_t)node * K);
    int4 i0 = ip[0], i1 = ip[1];

    const unsigned char* gp = g8c + (size_t)grp * N_NODES * GW + h * 16;
    f32x2 acc2[8];
#pragma unroll
    for (int j = 0; j < 8; ++j) acc2[j] = (f32x2){0.f, 0.f};

    // batch 1: 8 gathers in flight, then decode
    {
        uint4 u[8];
        u[0] = *(const uint4*)(gp + (size_t)i0.x * GW);
        u[1] = *(const uint4*)(gp + (size_t)i0.y * GW);
        u[2] = *(const uint4*)(gp + (size_t)i0.z * GW);
        u[3] = *(const uint4*)(gp + (size_t)i0.w * GW);
        u[4] = *(const uint4*)(gp + (size_t)i1.x * GW);
        u[5] = *(const uint4*)(gp + (size_t)i1.y * GW);
        u[6] = *(const uint4*)(gp + (size_t)i1.z * GW);
        u[7] = *(const uint4*)(gp + (size_t)i1.w * GW);
        int4 i2 = ip[2], i3 = ip[3];   // next idx under batch-1 flight
#pragma unroll
        for (int k = 0; k < 8; ++k) {
            dec4p(u[k].x, acc2 + 0);
            dec4p(u[k].y, acc2 + 2);
            dec4p(u[k].z, acc2 + 4);
            dec4p(u[k].w, acc2 + 6);
        }
        // batch 2
        u[0] = *(const uint4*)(gp + (size_t)i2.x * GW);
        u[1] = *(const uint4*)(gp + (size_t)i2.y * GW);
        u[2] = *(const uint4*)(gp + (size_t)i2.z * GW);
        u[3] = *(const uint4*)(gp + (size_t)i2.w * GW);
        u[4] = *(const uint4*)(gp + (size_t)i3.x * GW);
        u[5] = *(const uint4*)(gp + (size_t)i3.y * GW);
        u[6] = *(const uint4*)(gp + (size_t)i3.z * GW);
        u[7] = *(const uint4*)(gp + (size_t)i3.w * GW);
#pragma unroll
        for (int k = 0; k < 8; ++k) {
            dec4p(u[k].x, acc2 + 0);
            dec4p(u[k].y, acc2 + 2);
            dec4p(u[k].z, acc2 + 4);
            dec4p(u[k].w, acc2 + 6);
        }
    }

    unsigned pk[8];
#pragma unroll
    for (int j = 0; j < 8; ++j) {
        unsigned short a = f2bf(acc2[j].x * (1.f / 16.f));
        unsigned short b = f2bf(acc2[j].y * (1.f / 16.f));
        pk[j] = (unsigned)a | ((unsigned)b << 16);
    }
    unsigned short* op = aggc + ((size_t)grp * N_NODES + node) * GW + h * 16;
    *(uint4*)op       = make_uint4(pk[0], pk[1], pk[2], pk[3]);
    *(uint4*)(op + 8) = make_uint4(pk[4], pk[5], pk[6], pk[7]);
}

// Regular half: streaming self+agg -> cat LDS -> MFMA -> epilogue.
// agg and the fp8 h-output use the column-blocked layout [grp][node][GW].
// LAYER==0: self from f32 feats; outputs h1 bf16 + h1 fp8(blocked)
// LAYER==1: self from bf16 h1; outputs z f32 directly from accumulators
template <int LAYER>
__launch_bounds__(256, 4)
__global__ void sage_mm(const float* __restrict__ self_f32,
                        const unsigned short* __restrict__ self_bf,
                        const unsigned short* __restrict__ aggc,
                        const unsigned short* __restrict__ Wt,
                        const float* __restrict__ bias,
                        unsigned short* __restrict__ h_out,
                        unsigned char* __restrict__ h8c_out,
                        float* __restrict__ z_out) {
    __shared__ __align__(16) char smraw[MB * LDSW * 2];   // 16896 B, dual-purpose
    unsigned short (*cat)[LDSW] = (unsigned short (*)[LDSW])smraw;
    float (*zb)[ZW] = (float (*)[ZW])smraw;

    const int t = threadIdx.x;
    const int base = blockIdx.x * MB;
    const int lane = t & 63;
    const int wave = t >> 6;
    const int q = lane >> 4;
    const int nlo = lane & 15;

    // ---- stage cat = [self | agg] into LDS (all streaming) ----
    {
        const int m = t >> 3;
        const int c = (t & 7) * 16;
        const int node = base + m;
        const int sub = t & 7;

        // agg half (bf16, column-blocked): cols c..c+15 live at
        // aggc[(sub>>1)*N + node][ (sub&1)*16 .. ]
        const uint4* ap = (const uint4*)(aggc + ((size_t)(sub >> 1) * N_NODES + node) * GW + (sub & 1) * 16);
        uint4 a0 = ap[0], a1 = ap[1];

        if (LAYER == 0) {
            const float4* sp = (const float4*)(self_f32 + (size_t)node * D + c);
            float sv[16];
            *(f32x4*)&sv[0]  = *(const f32x4*)&sp[0];
            *(f32x4*)&sv[4]  = *(const f32x4*)&sp[1];
            *(f32x4*)&sv[8]  = *(const f32x4*)&sp[2];
            *(f32x4*)&sv[12] = *(const f32x4*)&sp[3];
            unsigned w[8];
#pragma unroll
            for (int j = 0; j < 8; ++j)
                w[j] = (unsigned)f2bf(sv[2 * j]) | ((unsigned)f2bf(sv[2 * j + 1]) << 16);
            *(uint4*)&cat[m][c]     = make_uint4(w[0], w[1], w[2], w[3]);
            *(uint4*)&cat[m][c + 8] = make_uint4(w[4], w[5], w[6], w[7]);
        } else {
            const uint4* sp = (const uint4*)(self_bf + (size_t)node * D + c);
            uint4 sb0 = sp[0], sb1 = sp[1];
            *(uint4*)&cat[m][c]     = sb0;
            *(uint4*)&cat[m][c + 8] = sb1;
        }

        *(uint4*)&cat[m][D + c]     = a0;
        *(uint4*)&cat[m][D + c + 8] = a1;
    }

    // ---- per-wave B fragments (32 output cols, K=256) ----
    bf16x8 bfrag[2][8];
#pragma unroll
    for (int ct = 0; ct < 2; ++ct) {
        int n = wave * 32 + ct * 16 + nlo;
        const unsigned short* wp = Wt + n * CATK + q * 8;
#pragma unroll
        for (int ks = 0; ks < 8; ++ks)
            bfrag[ct][ks] = *(const bf16x8*)(wp + ks * 32);
    }

    __syncthreads();

    // ---- MFMA: [32 x 256] x [256 x 32(this wave)] ----
    f32x4 acc00 = {}, acc01 = {}, acc10 = {}, acc11 = {};
#pragma unroll
    for (int ks = 0; ks < 8; ++ks) {
        bf16x8 a0 = *(const bf16x8*)&cat[nlo][ks * 32 + q * 8];
        bf16x8 a1 = *(const bf16x8*)&cat[16 + nlo][ks * 32 + q * 8];
        acc00 = __builtin_amdgcn_mfma_f32_16x16x32_bf16(a0, bfrag[0][ks], acc00, 0, 0, 0);
        acc01 = __builtin_amdgcn_mfma_f32_16x16x32_bf16(a0, bfrag[1][ks], acc01, 0, 0, 0);
        acc10 = __builtin_amdgcn_mfma_f32_16x16x32_bf16(a1, bfrag[0][ks], acc10, 0, 0, 0);
        acc11 = __builtin_amdgcn_mfma_f32_16x16x32_bf16(a1, bfrag[1][ks], acc11, 0, 0, 0);
    }

    if (LAYER == 1) {
        // direct f32 store from accumulator layout (col = lane&15+..., row = q*4+r)
#pragma unroll
        for (int ct = 0; ct < 2; ++ct) {
            int col = wave * 32 + ct * 16 + nlo;
            float bv = bias[col];
            f32x4 v0 = (ct == 0) ? acc00 : acc01;
            f32x4 v1 = (ct == 0) ? acc10 : acc11;
#pragma unroll
            for (int r = 0; r < 4; ++r) {
                z_out[(size_t)(base + q * 4 + r) * D + col]      = v0[r] + bv;
                z_out[(size_t)(base + 16 + q * 4 + r) * D + col] = v1[r] + bv;
            }
        }
        return;
    }

    // LAYER 0: stage z into LDS (reuse cat memory) for col-pair bf16/fp8 packing
    __syncthreads();
#pragma unroll
    for (int ct = 0; ct < 2; ++ct) {
        int col = wave * 32 + ct * 16 + nlo;
        float bv = bias[col];
        f32x4 v0 = (ct == 0) ? acc00 : acc01;
        f32x4 v1 = (ct == 0) ? acc10 : acc11;
#pragma unroll
        for (int r = 0; r < 4; ++r) {
            zb[q * 4 + r][col]      = v0[r] + bv;
            zb[16 + q * 4 + r][col] = v1[r] + bv;
        }
    }
    __syncthreads();
    {
        const int m = t >> 3;
        const int c = (t & 7) * 16;
        const int sub = t & 7;
        float x[16];
        *(f32x4*)&x[0]  = *(const f32x4*)&zb[m][c];
        *(f32x4*)&x[4]  = *(const f32x4*)&zb[m][c + 4];
        *(f32x4*)&x[8]  = *(const f32x4*)&zb[m][c + 8];
        *(f32x4*)&x[12] = *(const f32x4*)&zb[m][c + 12];
        size_t go = (size_t)(base + m) * D + c;
#pragma unroll
        for (int i = 0; i < 16; ++i) x[i] = x[i] > 0.f ? x[i] : 0.f;
        unsigned wb[8];
#pragma unroll
        for (int j = 0; j < 8; ++j)
            wb[j] = (unsigned)f2bf(x[2 * j]) | ((unsigned)f2bf(x[2 * j + 1]) << 16);
        uint4* hp = (uint4*)(h_out + go);
        hp[0] = make_uint4(wb[0], wb[1], wb[2], wb[3]);
        hp[1] = make_uint4(wb[4], wb[5], wb[6], wb[7]);
        uint4 o8;
        o8.x = pk4(x[0], x[1], x[2], x[3]);
        o8.y = pk4(x[4], x[5], x[6], x[7]);
        o8.z = pk4(x[8], x[9], x[10], x[11]);
        o8.w = pk4(x[12], x[13], x[14], x[15]);
        // fp8 h1 in column-blocked layout for layer-1 gather
        *(uint4*)(h8c_out + ((size_t)(sub >> 1) * N_NODES + (size_t)(base + m)) * GW + (sub & 1) * 16) = o8;
    }
}

extern "C" void kernel_launch(void* const* d_in, const int* in_sizes, int n_in,
                              void* d_out, int out_size, void* d_ws, size_t ws_size,
                              hipStream_t stream) {
    const float* feats = (const float*)d_in[0];
    const int* neigh   = (const int*)d_in[1];
    const float* Ws    = (const float*)d_in[2];
    const float* bs    = (const float*)d_in[3];
    float* out = (float*)d_out;

    char* ws = (char*)d_ws;
    unsigned short* h1_bf  = (unsigned short*)(ws);                 // 25,600,000 B
    unsigned char*  feats8 = (unsigned char*)(ws + 25600000);       // 12,800,000 B (column-blocked)
    unsigned char*  h18    = (unsigned char*)(ws + 38400000);       // 12,800,000 B (column-blocked)
    unsigned short* Wt     = (unsigned short*)(ws + 51200000);      //    131,072 B
    unsigned short* agg    = (unsigned short*)(ws + 51331072);      // 25,600,000 B (column-blocked)

    cvt_all<<<3125, 256, 0, stream>>>(feats, Ws, feats8, Wt);

    // gather grid: 8 xcd-slots x 391 = 3128 blocks; 128 nodes/block;
    // (wg%8)>>1 = column group, (wg>>3)*2+(wg&1) = node block (0..781)
    gather_mean<<<3128, 256, 0, stream>>>(feats8, neigh, agg);
    sage_mm<0><<<N_NODES / MB, 256, 0, stream>>>(
        feats, nullptr, agg, Wt, bs, h1_bf, h18, nullptr);

    gather_mean<<<3128, 256, 0, stream>>>(h18, neigh + N_NODES * K, agg);
    sage_mm<1><<<N_NODES / MB, 256, 0, stream>>>(
        nullptr, h1_bf, agg, Wt + CATK * D, bs + D,
        nullptr, nullptr, out);
}

// Round 10
// 190.643 us; speedup vs baseline: 1.2547x; 1.2547x over previous
//
#include <hip/hip_runtime.h>

#define N_NODES 100000
#define D 128          // feature dim
#define K 16           // neighbors
#define CATK 256       // concat dim (2*D)
#define MB 64          // nodes per block (512 threads, 8 waves)
#define NT 512
#define NBLK ((N_NODES + MB - 1) / MB)   // 1563 (last block: 32 valid rows)
#define PAD 8
#define LDSW (CATK + PAD)   // 264 bf16 elems -> 528 B row stride
#define ZW 132              // z-staging row stride in floats (528 B)

typedef __attribute__((ext_vector_type(8))) short bf16x8;
typedef __attribute__((ext_vector_type(4))) float f32x4;
typedef __attribute__((ext_vector_type(2))) float f32x2;

__device__ __forceinline__ unsigned short f2bf(float f) {
    union { float f; unsigned u; } v; v.f = f;
    unsigned u = v.u;
    return (unsigned short)((u + 0x7fffu + ((u >> 16) & 1u)) >> 16);  // RNE
}

// pack 4 floats -> 4 fp8 e4m3 bytes
__device__ __forceinline__ unsigned pk4(float a, float b, float c, float d) {
    int w = __builtin_amdgcn_cvt_pk_fp8_f32(a, b, 0, false);
    w = __builtin_amdgcn_cvt_pk_fp8_f32(c, d, w, true);
    return (unsigned)w;
}

// decode 4 fp8 bytes, accumulate into two packed f32x2 accumulators
__device__ __forceinline__ void dec4p(unsigned w, f32x2* a) {
    f32x2 lo = __builtin_amdgcn_cvt_pk_f32_fp8((int)w, false);
    f32x2 hi = __builtin_amdgcn_cvt_pk_f32_fp8((int)w, true);
    a[0] += lo;
    a[1] += hi;
}

// feats f32 -> fp8 table; also Ws [2,256,128] f32 -> Wt [2,128,256] bf16 (transposed)
__global__ void cvt_all(const float* __restrict__ feats, const float* __restrict__ Ws,
                        unsigned* __restrict__ f8, unsigned short* __restrict__ Wt) {
    int tid = blockIdx.x * 256 + threadIdx.x;
    int i = tid * 16;
    if (i < N_NODES * D) {
        const float4* p = (const float4*)(feats + i);
        float4 v0 = p[0], v1 = p[1], v2 = p[2], v3 = p[3];
        uint4 o;
        o.x = pk4(v0.x, v0.y, v0.z, v0.w);
        o.y = pk4(v1.x, v1.y, v1.z, v1.w);
        o.z = pk4(v2.x, v2.y, v2.z, v2.w);
        o.w = pk4(v3.x, v3.y, v3.z, v3.w);
        *(uint4*)(f8 + i / 4) = o;
    }
    if (tid < 2 * CATK * D) {
        int l = tid / (CATK * D);
        int r = tid % (CATK * D);
        int n = r / CATK, k = r % CATK;
        Wt[tid] = f2bf(Ws[l * CATK * D + k * D + n]);
    }
}

// One GraphSAGE layer: gather(fp8)+mean+concat+GEMM(+bias)(+relu), FUSED
// (splits lost: R8 +18us, R9 +38us -- agg round-trip costs more than it saves).
// MB=64: each block loads the full 64KB Wt once; at MB=32 that was 200 MB/layer
// of L2 line-traffic (equal to the entire gather). MB=16 (R7) doubled it and
// cost +24us/layer -- this halves it. Per-wave B-fragment is now 16 cols
// (bfrag[8]=32 VGPRs + acc[4]=16), LOWER pressure than R1's 2x32-col layout.
// LAYER==0: self from f32 feats; outputs h1 bf16 + h1 fp8
// LAYER==1: self from bf16 h1; outputs z f32 directly from accumulators
template <int LAYER>
__launch_bounds__(NT, 4)
__global__ void sage_layer(const float* __restrict__ self_f32,
                           const unsigned short* __restrict__ self_bf,
                           const unsigned char* __restrict__ g8,
                           const int* __restrict__ idx,
                           const unsigned short* __restrict__ Wt,
                           const float* __restrict__ bias,
                           unsigned short* __restrict__ h_out,
                           unsigned char* __restrict__ h8_out,
                           float* __restrict__ z_out) {
    __shared__ __align__(16) char smraw[MB * LDSW * 2];   // 33792 B, dual-purpose
    unsigned short (*cat)[LDSW] = (unsigned short (*)[LDSW])smraw;
    float (*zb)[ZW] = (float (*)[ZW])smraw;

    const int t = threadIdx.x;
    const int base = blockIdx.x * MB;
    const int lane = t & 63;
    const int wave = t >> 6;          // 0..7
    const int q = lane >> 4;          // 0..3
    const int nlo = lane & 15;

    // ---- gather(fp8) + mean + self + concat into LDS (bf16) ----
    {
        const int m = t >> 3;            // node in tile (0..63)
        const int c = (t & 7) * 16;      // 16-element column slice
        int node = base + m;
        if (node >= N_NODES) node = N_NODES - 1;   // clamp reads (tail block)

        // neighbor indices: 8 lanes share each 16B chunk -> in-wave broadcast
        const int4* ip = (const int4*)(idx + (size_t)node * K);
        int4 i0 = ip[0], i1 = ip[1];

        // self part (overlaps with idx/gather latency)
        if (LAYER == 0) {
            const float4* sp = (const float4*)(self_f32 + (size_t)node * D + c);
            float sv[16];
            *(f32x4*)&sv[0]  = *(const f32x4*)&sp[0];
            *(f32x4*)&sv[4]  = *(const f32x4*)&sp[1];
            *(f32x4*)&sv[8]  = *(const f32x4*)&sp[2];
            *(f32x4*)&sv[12] = *(const f32x4*)&sp[3];
            unsigned w[8];
#pragma unroll
            for (int j = 0; j < 8; ++j)
                w[j] = (unsigned)f2bf(sv[2 * j]) | ((unsigned)f2bf(sv[2 * j + 1]) << 16);
            *(uint4*)&cat[m][c]     = make_uint4(w[0], w[1], w[2], w[3]);
            *(uint4*)&cat[m][c + 8] = make_uint4(w[4], w[5], w[6], w[7]);
        } else {
            const uint4* sp = (const uint4*)(self_bf + (size_t)node * D + c);
            uint4 sb0 = sp[0], sb1 = sp[1];
            *(uint4*)&cat[m][c]     = sb0;
            *(uint4*)&cat[m][c + 8] = sb1;
        }

        const unsigned char* gp = g8 + c;
        f32x2 acc2[8];
#pragma unroll
        for (int j = 0; j < 8; ++j) acc2[j] = (f32x2){0.f, 0.f};

        // batch 1: 8 gathers in flight, then decode
        {
            uint4 u[8];
            u[0] = *(const uint4*)(gp + (size_t)i0.x * D);
            u[1] = *(const uint4*)(gp + (size_t)i0.y * D);
            u[2] = *(const uint4*)(gp + (size_t)i0.z * D);
            u[3] = *(const uint4*)(gp + (size_t)i0.w * D);
            u[4] = *(const uint4*)(gp + (size_t)i1.x * D);
            u[5] = *(const uint4*)(gp + (size_t)i1.y * D);
            u[6] = *(const uint4*)(gp + (size_t)i1.z * D);
            u[7] = *(const uint4*)(gp + (size_t)i1.w * D);
            // issue next idx load while batch-1 data is in flight
            int4 i2 = ip[2], i3 = ip[3];
#pragma unroll
            for (int k = 0; k < 8; ++k) {
                dec4p(u[k].x, acc2 + 0);
                dec4p(u[k].y, acc2 + 2);
                dec4p(u[k].z, acc2 + 4);
                dec4p(u[k].w, acc2 + 6);
            }
            // batch 2
            u[0] = *(const uint4*)(gp + (size_t)i2.x * D);
            u[1] = *(const uint4*)(gp + (size_t)i2.y * D);
            u[2] = *(const uint4*)(gp + (size_t)i2.z * D);
            u[3] = *(const uint4*)(gp + (size_t)i2.w * D);
            u[4] = *(const uint4*)(gp + (size_t)i3.x * D);
            u[5] = *(const uint4*)(gp + (size_t)i3.y * D);
            u[6] = *(const uint4*)(gp + (size_t)i3.z * D);
            u[7] = *(const uint4*)(gp + (size_t)i3.w * D);
#pragma unroll
            for (int k = 0; k < 8; ++k) {
                dec4p(u[k].x, acc2 + 0);
                dec4p(u[k].y, acc2 + 2);
                dec4p(u[k].z, acc2 + 4);
                dec4p(u[k].w, acc2 + 6);
            }
        }

        unsigned pk[8];
#pragma unroll
        for (int j = 0; j < 8; ++j) {
            unsigned short a = f2bf(acc2[j].x * (1.f / 16.f));
            unsigned short b = f2bf(acc2[j].y * (1.f / 16.f));
            pk[j] = (unsigned)a | ((unsigned)b << 16);
        }
        *(uint4*)&cat[m][D + c]     = make_uint4(pk[0], pk[1], pk[2], pk[3]);
        *(uint4*)&cat[m][D + c + 8] = make_uint4(pk[4], pk[5], pk[6], pk[7]);
    }

    // ---- per-wave B fragments (16 output cols, K=256) ----
    bf16x8 bfrag[8];
    {
        int n = wave * 16 + nlo;
        const unsigned short* wp = Wt + n * CATK + q * 8;
#pragma unroll
        for (int ks = 0; ks < 8; ++ks)
            bfrag[ks] = *(const bf16x8*)(wp + ks * 32);
    }

    __syncthreads();

    // ---- MFMA: [64 x 256] x [256 x 16(this wave)] ----
    f32x4 acc[4] = {{}, {}, {}, {}};
#pragma unroll
    for (int ks = 0; ks < 8; ++ks) {
#pragma unroll
        for (int rt = 0; rt < 4; ++rt) {
            bf16x8 a = *(const bf16x8*)&cat[rt * 16 + nlo][ks * 32 + q * 8];
            acc[rt] = __builtin_amdgcn_mfma_f32_16x16x32_bf16(a, bfrag[ks], acc[rt], 0, 0, 0);
        }
    }

    if (LAYER == 1) {
        // direct f32 store from accumulator layout: col = wave*16+nlo, row = rt*16+q*4+r
        int col = wave * 16 + nlo;
        float bv = bias[col];
#pragma unroll
        for (int rt = 0; rt < 4; ++rt) {
#pragma unroll
            for (int r = 0; r < 4; ++r) {
                int row = base + rt * 16 + q * 4 + r;
                if (row < N_NODES)
                    z_out[(size_t)row * D + col] = acc[rt][r] + bv;
            }
        }
        return;
    }

    // LAYER 0: stage z into LDS (reuse cat memory) for col-pair bf16/fp8 packing
    __syncthreads();
    {
        int col = wave * 16 + nlo;
        float bv = bias[col];
#pragma unroll
        for (int rt = 0; rt < 4; ++rt) {
#pragma unroll
            for (int r = 0; r < 4; ++r)
                zb[rt * 16 + q * 4 + r][col] = acc[rt][r] + bv;
        }
    }
    __syncthreads();
    {
        const int m = t >> 3;
        const int c = (t & 7) * 16;
        const int node = base + m;
        if (node < N_NODES) {
            float x[16];
            *(f32x4*)&x[0]  = *(const f32x4*)&zb[m][c];
            *(f32x4*)&x[4]  = *(const f32x4*)&zb[m][c + 4];
            *(f32x4*)&x[8]  = *(const f32x4*)&zb[m][c + 8];
            *(f32x4*)&x[12] = *(const f32x4*)&zb[m][c + 12];
            size_t go = (size_t)node * D + c;
#pragma unroll
            for (int i = 0; i < 16; ++i) x[i] = x[i] > 0.f ? x[i] : 0.f;
            unsigned wb[8];
#pragma unroll
            for (int j = 0; j < 8; ++j)
                wb[j] = (unsigned)f2bf(x[2 * j]) | ((unsigned)f2bf(x[2 * j + 1]) << 16);
            uint4* hp = (uint4*)(h_out + go);
            hp[0] = make_uint4(wb[0], wb[1], wb[2], wb[3]);
            hp[1] = make_uint4(wb[4], wb[5], wb[6], wb[7]);
            uint4 o8;
            o8.x = pk4(x[0], x[1], x[2], x[3]);
            o8.y = pk4(x[4], x[5], x[6], x[7]);
            o8.z = pk4(x[8], x[9], x[10], x[11]);
            o8.w = pk4(x[12], x[13], x[14], x[15]);
            *(uint4*)(h8_out + go) = o8;
        }
    }
}

extern "C" void kernel_launch(void* const* d_in, const int* in_sizes, int n_in,
                              void* d_out, int out_size, void* d_ws, size_t ws_size,
                              hipStream_t stream) {
    const float* feats = (const float*)d_in[0];
    const int* neigh   = (const int*)d_in[1];
    const float* Ws    = (const float*)d_in[2];
    const float* bs    = (const float*)d_in[3];
    float* out = (float*)d_out;

    char* ws = (char*)d_ws;
    unsigned short* h1_bf  = (unsigned short*)(ws);                 // 25,600,000 B
    unsigned char*  feats8 = (unsigned char*)(ws + 25600000);       // 12,800,000 B
    unsigned char*  h18    = (unsigned char*)(ws + 38400000);       // 12,800,000 B
    unsigned short* Wt     = (unsigned short*)(ws + 51200000);      //    131,072 B

    cvt_all<<<3125, 256, 0, stream>>>(feats, Ws, (unsigned*)feats8, Wt);

    sage_layer<0><<<NBLK, NT, 0, stream>>>(
        feats, nullptr, feats8, neigh, Wt, bs, h1_bf, h18, nullptr);
    sage_layer<1><<<NBLK, NT, 0, stream>>>(
        nullptr, h1_bf, h18, neigh + N_NODES * K, Wt + CATK * D, bs + D,
        nullptr, nullptr, out);
}